// Round 1
// 282.778 us; speedup vs baseline: 1.0293x; 1.0293x over previous
//
#include <hip/hip_runtime.h>
#include <hip/hip_bf16.h>
#include <cstdint>

#define TSEQ 4096
#define CDIM 2048
#define HDIM 128

typedef short bf8v __attribute__((ext_vector_type(8)));  // 8 bf16 raw bits (4 VGPRs)
typedef float f4v  __attribute__((ext_vector_type(4)));

__device__ __forceinline__ unsigned short f2b(float f) {
  union { float f; unsigned u; } v; v.f = f;
  unsigned u = v.u;
  return (unsigned short)((u + 0x7fffu + ((u >> 16) & 1u)) >> 16);  // RNE
}

__device__ __forceinline__ f4v mfma16(bf8v a, bf8v b, f4v c) {
  return __builtin_amdgcn_mfma_f32_16x16x32_bf16(a, b, c, 0, 0, 0);
}

__device__ __forceinline__ void gload_lds16(const void* g, void* l) {
  __builtin_amdgcn_global_load_lds(
      (const __attribute__((address_space(1))) unsigned int*)g,
      (__attribute__((address_space(3))) unsigned int*)l, 16, 0, 0);
}

// ---------------- Kernel 1: Wq|Wk|Wv fp32 -> Wcat bf16 [384][2048] ----------------
__global__ void wcat_kernel(const float* __restrict__ Wq, const float* __restrict__ Wk,
                            const float* __restrict__ Wv, unsigned short* __restrict__ Wcat) {
  int e = (blockIdx.x * 256 + threadIdx.x) * 4;
  int n = e >> 11;
  int k = e & 2047;
  const float* src;
  if (n < 128)      src = Wq + (size_t)n * CDIM + k;
  else if (n < 256) src = Wk + (size_t)(n - 128) * CDIM + k;
  else              src = Wv + (size_t)(n - 256) * CDIM + k;
  float4 f = *(const float4*)src;
  ushort4 o;
  o.x = f2b(f.x); o.y = f2b(f.y); o.z = f2b(f.z); o.w = f2b(f.w);
  *(ushort4*)(Wcat + e) = o;
}

// ---------------- Kernel 2: proj GEMM v4 — read A ONCE for all 384 cols ----------
// 256 blocks x 64 rows (1 block/CU), 512 thr (8 waves), BK=64, full-N=384 tile.
// A (fp32, 134 MB) fetched from HBM exactly once -> HBM-bound floor ~21 us.
// B staged via global_load_lds(16B) with m201-style source-granule XOR swizzle
// (gd ^ (n&7)) so the linear [384][64] LDS tile is bank-conflict-free on
// ds_read_b128 frag reads. A reg-staged fp32->bf16 into pad-72 tile (2-way, free).
// Wave w owns output cols [w*48, w*48+48): acc[4][3], 24 MFMA per K-step.
__global__ __launch_bounds__(512, 2) void proj_gemm(const float* __restrict__ A,
                                                    const unsigned short* __restrict__ Bw,
                                                    unsigned short* __restrict__ QB,
                                                    unsigned short* __restrict__ KA,
                                                    unsigned short* __restrict__ VB) {
  __shared__ union {
    struct { unsigned short As[2][64][72]; unsigned short Bs[2][384][64]; } st;  // 114 KB
    unsigned short Ct[64][392];                                                  // 49 KB
  } sm;
  const int m0 = blockIdx.x * 64;
  const int tid = threadIdx.x;
  const int lane = tid & 63;
  const int w = tid >> 6;                 // 8 waves; wave w -> cols w*48..w*48+47
  const int llo = lane & 15, lhi = lane >> 4;

  f4v acc[4][3];
#pragma unroll
  for (int i = 0; i < 4; ++i)
#pragma unroll
    for (int j = 0; j < 3; ++j) acc[i][j] = (f4v){0.f, 0.f, 0.f, 0.f};

  // A staging: 2 float4 per thread (64x64 fp32 tile = 1024 granules / 512 thr)
  const int ar0 = tid >> 4;               // rows 0..31 (p=0) / +32 (p=1)
  const int ac0 = (tid & 15) * 4;
  const float* aptr0 = A + (size_t)(m0 + ar0) * CDIM + ac0;
  const float* aptr1 = A + (size_t)(m0 + 32 + ar0) * CDIM + ac0;

  // B staging: 6 global_load_lds per wave per K-step (48 rows x 64 k).
  // dest granule (n, lane&7) holds source granule (lane&7)^(n&7); n&7 == lane>>3.
  const int brow = lane >> 3;             // 0..7
  const int bgs  = (lane & 7) ^ brow;     // pre-swizzled source granule
  const unsigned short* bptr = Bw + (size_t)(w * 48 + brow) * CDIM + bgs * 8;

  // ---- prologue: stage K-tile 0 into buf 0 ----
  float4 fa0 = *(const float4*)(aptr0);
  float4 fa1 = *(const float4*)(aptr1);
#pragma unroll
  for (int j = 0; j < 6; ++j)
    gload_lds16(bptr + (size_t)j * 8 * CDIM, &sm.st.Bs[0][w * 48 + j * 8][0]);
  {
    ushort4 o0, o1;
    o0.x = f2b(fa0.x); o0.y = f2b(fa0.y); o0.z = f2b(fa0.z); o0.w = f2b(fa0.w);
    o1.x = f2b(fa1.x); o1.y = f2b(fa1.y); o1.z = f2b(fa1.z); o1.w = f2b(fa1.w);
    *(ushort4*)&sm.st.As[0][ar0][ac0]      = o0;
    *(ushort4*)&sm.st.As[0][32 + ar0][ac0] = o1;
  }

  for (int it = 0; it < 32; ++it) {
    const int cur = it & 1;
    __syncthreads();
    if (it < 31) {
      // A prefetch first (so its vmcnt wait leaves the B loads in flight)
      fa0 = *(const float4*)(aptr0 + (it + 1) * 64);
      fa1 = *(const float4*)(aptr1 + (it + 1) * 64);
      const int nxt = cur ^ 1;
#pragma unroll
      for (int j = 0; j < 6; ++j)
        gload_lds16(bptr + (size_t)j * 8 * CDIM + (it + 1) * 64,
                    &sm.st.Bs[nxt][w * 48 + j * 8][0]);
    }
#pragma unroll
    for (int kk = 0; kk < 2; ++kk) {
      bf8v af[4], bf[3];
#pragma unroll
      for (int i = 0; i < 4; ++i)
        af[i] = *(const bf8v*)&sm.st.As[cur][i * 16 + llo][kk * 32 + lhi * 8];
#pragma unroll
      for (int j = 0; j < 3; ++j) {
        const int n = w * 48 + j * 16 + llo;
        bf[j] = *(const bf8v*)&sm.st.Bs[cur][n][(((kk << 2) + lhi) ^ (llo & 7)) * 8];
      }
#pragma unroll
      for (int i = 0; i < 4; ++i)
#pragma unroll
        for (int j = 0; j < 3; ++j) acc[i][j] = mfma16(af[i], bf[j], acc[i][j]);
    }
    if (it < 31) {
      const int nxt = cur ^ 1;
      ushort4 o0, o1;
      o0.x = f2b(fa0.x); o0.y = f2b(fa0.y); o0.z = f2b(fa0.z); o0.w = f2b(fa0.w);
      o1.x = f2b(fa1.x); o1.y = f2b(fa1.y); o1.z = f2b(fa1.z); o1.w = f2b(fa1.w);
      *(ushort4*)&sm.st.As[nxt][ar0][ac0]      = o0;
      *(ushort4*)&sm.st.As[nxt][32 + ar0][ac0] = o1;
    }
  }

  // ---- epilogue: stage 64x384 C tile in LDS, then emit the verified layouts ----
  __syncthreads();
#pragma unroll
  for (int i = 0; i < 4; ++i)
#pragma unroll
    for (int j = 0; j < 3; ++j)
#pragma unroll
      for (int r = 0; r < 4; ++r)
        sm.Ct[i * 16 + lhi * 4 + r][w * 48 + j * 16 + llo] = f2b(acc[i][j][r]);
  __syncthreads();

  // Q (cols 0..127) and K (cols 128..255): A-fragment layout, same as before
  {
    const size_t base16 = (size_t)(m0 >> 4);
#pragma unroll
    for (int yy = 0; yy < 2; ++yy) {
      unsigned short* dst = yy ? KA : QB;
      const int colb = yy * 128;
#pragma unroll
      for (int p = 0; p < 2; ++p) {
        int g = p * 512 + tid;
        int t16l = g >> 8, kk2 = (g >> 6) & 3, ln = g & 63;
        int lo = ln & 15, hi = ln >> 4;
        bf8v v = *(const bf8v*)&sm.Ct[t16l * 16 + lo][colb + kk2 * 32 + hi * 8];
        *(bf8v*)(dst + (((base16 + t16l) * 4 + kk2) * 64 + ln) * 8) = v;
      }
    }
  }
  // V (cols 256..383): transposed B-fragment layout + ones column (ht=8)
  {
    const size_t base32 = (size_t)(m0 >> 5);
#pragma unroll
    for (int p = 0; p < 3; ++p) {
      int g = p * 512 + tid;
      if (g < 1152) {
        int jbl = g / 576;
        int ht  = (g % 576) >> 6;
        int ln  = g & 63;
        int lo = ln & 15, hi = ln >> 4;
        bf8v v;
        if (ht == 8) {
#pragma unroll
          for (int e = 0; e < 8; ++e) v[e] = (lo == 0) ? (short)0x3F80 : (short)0;
        } else {
#pragma unroll
          for (int e = 0; e < 8; ++e) v[e] = (short)sm.Ct[jbl * 32 + hi * 8 + e][256 + ht * 16 + lo];
        }
        *(bf8v*)(VB + (((base32 + jbl) * 9 + ht) * 512 + (size_t)ln * 8)) = v;
      }
    }
  }
}

// ---------------- Kernel 3: flash attention v6 — software-pipelined, no spills -----
// (unchanged)
__global__ __launch_bounds__(256, 4) void attn6(const unsigned short* __restrict__ QB,
                                                const unsigned short* __restrict__ KA,
                                                const unsigned short* __restrict__ VB,
                                                float* __restrict__ out) {
  __shared__ union SM {
    unsigned short Ps[4][2][16][68];                      // [wave][buf][row][col] 17.4 KB
    struct { float Om[4][16][68]; float Lm[4][16]; } mg;  // 17.7 KB
  } sm;
  const int x = blockIdx.x;
  const int b = x & 3;
  const int u = x >> 2;
  const int g = u >> 6, r0 = u & 63;
  const int s = (g & 1) ? (g * 64 + 63 - r0) : (g * 64 + r0);
  const int lastjt = s >> 2;
  const int tid = threadIdx.x;
  const int w = tid >> 6, lane = tid & 63;
  const int llo = lane & 15, lhi = lane >> 4;
  const float scale = 0.022097086912079608f;  // 2048^-0.5

  bf8v aK[4];
  {
    const unsigned short* kp = KA + (size_t)(b * 256 + s) * 2048;
#pragma unroll
    for (int kk = 0; kk < 4; ++kk) aK[kk] = *(const bf8v*)(kp + (kk * 64 + lane) * 8);
  }

  f4v Oacc[9];
#pragma unroll
  for (int nt = 0; nt < 9; ++nt) Oacc[nt] = (f4v){0.f, 0.f, 0.f, 0.f};

  auto computeS = [&](int jtS, int buf) {
    const unsigned short* qp = QB + (size_t)(b * 256 + jtS * 4) * 2048;
#pragma unroll
    for (int ct = 0; ct < 4; ++ct) {
      f4v acc = (f4v){0.f, 0.f, 0.f, 0.f};
#pragma unroll
      for (int kk = 0; kk < 4; ++kk) {
        bf8v bq = *(const bf8v*)(qp + ((ct * 4 + kk) * 64 + lane) * 8);
        acc = mfma16(aK[kk], bq, acc);
      }
#pragma unroll
      for (int r = 0; r < 4; ++r) {
        float sv = acc[r];
        if (jtS == lastjt) {
          int j = jtS * 64 + ct * 16 + llo;
          int i = s * 16 + lhi * 4 + r;
          if (j > i) sv = -3.0e38f;
        }
        sm.Ps[w][buf][lhi * 4 + r][ct * 16 + llo] = f2b(__expf(sv * scale));
      }
    }
  };

  if (w <= lastjt) computeS(w, 0);
  int buf = 0;
  for (int jt = w; jt <= lastjt; jt += 4) {
    bf8v aP0 = *(const bf8v*)&sm.Ps[w][buf][llo][lhi * 8];
    bf8v aP1 = *(const bf8v*)&sm.Ps[w][buf][llo][32 + lhi * 8];
    if (jt + 4 <= lastjt) computeS(jt + 4, buf ^ 1);
    const unsigned short* vp = VB + (size_t)(b * 128 + jt * 2) * 4608;  // 9 ht * 512
#pragma unroll
    for (int nt = 0; nt < 9; ++nt) {
      f4v o = Oacc[nt];
      o = mfma16(aP0, *(const bf8v*)(vp + nt * 512 + (size_t)lane * 8), o);
      o = mfma16(aP1, *(const bf8v*)(vp + 4608 + nt * 512 + (size_t)lane * 8), o);
      Oacc[nt] = o;
    }
    buf ^= 1;
  }

#pragma unroll
  for (int half = 0; half < 2; ++half) {
    __syncthreads();
#pragma unroll
    for (int nt = 0; nt < 4; ++nt)
#pragma unroll
      for (int r = 0; r < 4; ++r)
        sm.mg.Om[w][lhi * 4 + r][nt * 16 + llo] = Oacc[half * 4 + nt][r];
    if (half == 0 && llo == 0) {
#pragma unroll
      for (int r = 0; r < 4; ++r) sm.mg.Lm[w][lhi * 4 + r] = Oacc[8][r];
    }
    __syncthreads();
    {
      int row = tid >> 4, c0 = (tid & 15) * 4;
      float L = sm.mg.Lm[0][row] + sm.mg.Lm[1][row] + sm.mg.Lm[2][row] + sm.mg.Lm[3][row];
      float inv = 1.0f / L;
      float* op = out + (size_t)(b * TSEQ + s * 16 + row) * HDIM + half * 64 + c0;
#pragma unroll
      for (int e = 0; e < 4; ++e) {
        float o = sm.mg.Om[0][row][c0 + e] + sm.mg.Om[1][row][c0 + e] +
                  sm.mg.Om[2][row][c0 + e] + sm.mg.Om[3][row][c0 + e];
        op[e] = o * inv;
      }
    }
  }
}

extern "C" void kernel_launch(void* const* d_in, const int* in_sizes, int n_in,
                              void* d_out, int out_size, void* d_ws, size_t ws_size,
                              hipStream_t stream) {
  const float* idx = (const float*)d_in[0];
  const float* Wq  = (const float*)d_in[1];
  const float* Wk  = (const float*)d_in[2];
  const float* Wv  = (const float*)d_in[3];
  float* out = (float*)d_out;
  char* ws = (char*)d_ws;
  unsigned short* Wcat = (unsigned short*)ws;                        // 1.57 MB
  unsigned short* QB   = (unsigned short*)(ws + ((size_t)2  << 20)); // 4.2 MB
  unsigned short* KA   = (unsigned short*)(ws + ((size_t)7  << 20)); // 4.2 MB
  unsigned short* VB   = (unsigned short*)(ws + ((size_t)12 << 20)); // 4.72 MB

  wcat_kernel<<<768, 256, 0, stream>>>(Wq, Wk, Wv, Wcat);
  proj_gemm<<<256, 512, 0, stream>>>(idx, Wcat, QB, KA, VB);
  attn6<<<1024, 256, 0, stream>>>(QB, KA, VB, out);
}